// Round 1
// baseline (5171.060 us; speedup 1.0000x reference)
//
#include <hip/hip_runtime.h>
#include <hip/hip_fp16.h>

typedef _Float16 h16;
typedef _Float16 v8h  __attribute__((ext_vector_type(8)));
typedef _Float16 v4hh __attribute__((ext_vector_type(4)));
typedef float    v4f  __attribute__((ext_vector_type(4)));

#define NPROD 16u

struct PParams {
  const float* x;                 // [64][512][256] fp32
  const float* Wih[4];            // [2048][KIN]
  const float* Whh[4];            // [2048][512]
  const float* bih[4];
  const float* bhh[4];
  h16* s[4];                      // streams: l=0..2 [512][64][512], l=3 [2][64][512]
  unsigned int* flags;            // [4][4][512]
};

__device__ inline float fsigmoid(float x){
  float e = __builtin_amdgcn_exp2f(-1.4426950408889634f * __builtin_fabsf(x));
  float r = __builtin_amdgcn_rcpf(1.0f + e);
  return x >= 0.f ? r : e * r;
}
__device__ inline float ftanhf(float x){
  float e = __builtin_amdgcn_exp2f(-2.8853900817779268f * __builtin_fabsf(x));
  float t = (1.0f - e) * __builtin_amdgcn_rcpf(1.0f + e);
  return x >= 0.f ? t : -t;
}

__device__ inline void wait_flag(const unsigned int* f, unsigned int tgt){
  int it = 0;
  while (__hip_atomic_load(f, __ATOMIC_RELAXED, __HIP_MEMORY_SCOPE_AGENT) < tgt){
    __builtin_amdgcn_s_sleep(1);
    if (++it > (1 << 22)) break;   // safety valve: never hang the harness
  }
}

// One LSTM layer slice: this wg owns 32 hidden units x 4 gates for 16 batches.
// Weights live in VGPRs as MFMA B-fragments. c stays in fp32 registers.
template<int KIN, bool XSRC>
__device__ void run_layer(const float* __restrict__ Wih, const float* __restrict__ Whh,
                          const float* __restrict__ bih, const float* __restrict__ bhh,
                          const float* __restrict__ xsrc,
                          const h16* __restrict__ src,
                          h16* __restrict__ dst, int dstMask,
                          unsigned int* flagSelf, unsigned int* flagSrc,
                          int rg, int bg, h16* A)
{
  const int tid  = threadIdx.x;
  const int wv   = tid >> 6;
  const int lane = tid & 63;
  const int ISTR = KIN + 8;       // padded LDS row stride (halves): 2-way banks = free
  const int HOFF = 8320;          // h-region offset (halves), stride 520
  const int KI   = KIN / 32;

  const int n16  = lane & 15;
  const int unit = rg*32 + wv*8 + (n16 & 7);
  const int ksub = ((lane >> 4) & 3) * 8;
  const int row0 = ((n16 >> 3)    ) * 512 + unit;   // gate i (n<8) / f (n>=8)
  const int row1 = ((n16 >> 3) + 2) * 512 + unit;   // gate g / o

  // ---- prologue: load weight slices into register fragments (one-time)
  v8h wihf[KI][2];
  v8h whhf[16][2];
  #pragma unroll
  for (int kk = 0; kk < KI; ++kk){
    #pragma unroll
    for (int j = 0; j < 2; ++j){
      const float* p = Wih + (size_t)(j ? row1 : row0) * KIN + kk*32 + ksub;
      v8h fr;
      #pragma unroll
      for (int e = 0; e < 8; ++e) fr[e] = (h16)p[e];
      wihf[kk][j] = fr;
    }
  }
  #pragma unroll
  for (int kk = 0; kk < 16; ++kk){
    #pragma unroll
    for (int j = 0; j < 2; ++j){
      const float* p = Whh + (size_t)(j ? row1 : row0) * 512 + kk*32 + ksub;
      v8h fr;
      #pragma unroll
      for (int e = 0; e < 8; ++e) fr[e] = (h16)p[e];
      whhf[kk][j] = fr;
    }
  }
  const float bias0 = bih[row0] + bhh[row0];
  const float bias1 = bih[row1] + bhh[row1];
  float c[4] = {0.f, 0.f, 0.f, 0.f};
  const bool hi = (lane & 8) != 0;

  #pragma unroll 1
  for (int t = 0; t < 512; ++t){
    // ---- dataflow wait: prev-layer output at t, own h at t-1
    if (tid == 0){
      if (!XSRC)  wait_flag(flagSrc + t, NPROD);
      if (t > 0)  wait_flag(flagSelf + (t - 1), NPROD);
      __builtin_amdgcn_fence(__ATOMIC_ACQUIRE, "agent");
    }
    __syncthreads();

    // ---- stage in(t) and h(t-1) into LDS (16 rows each)
    for (int q = tid; q < 2048; q += 256){
      int row = (q & 1023) >> 6;
      int col = q & 63;
      if (q < 1024){
        if (XSRC){
          const float4 v = *(const float4*)(xsrc + ((size_t)(bg*16 + row)*512 + t)*256 + col*4);
          v4hh o = { (h16)v.x, (h16)v.y, (h16)v.z, (h16)v.w };
          *(v4hh*)(A + row*ISTR + col*4) = o;
        } else {
          const uint4 v = *(const uint4*)(src + ((size_t)t*64 + bg*16 + row)*512 + col*8);
          *(uint4*)(A + row*ISTR + col*8) = v;
        }
      } else {
        uint4 v;
        if (t == 0) v = make_uint4(0u, 0u, 0u, 0u);
        else        v = *(const uint4*)(dst + ((size_t)((t-1) & dstMask)*64 + bg*16 + row)*512 + col*8);
        *(uint4*)(A + HOFF + row*520 + col*8) = v;
      }
    }
    __syncthreads();

    // ---- z = in @ Wih^T + h @ Whh^T  (fp32 accum in MFMA)
    v4f acc0 = {0.f, 0.f, 0.f, 0.f};
    v4f acc1 = {0.f, 0.f, 0.f, 0.f};
    const h16* Ain = A + (lane & 15)*ISTR + ksub;
    const h16* Ah  = A + HOFF + (lane & 15)*520 + ksub;
    #pragma unroll
    for (int kk = 0; kk < KI; ++kk){
      v8h a = *(const v8h*)(Ain + kk*32);
      acc0 = __builtin_amdgcn_mfma_f32_16x16x32_f16(a, wihf[kk][0], acc0, 0, 0, 0);
      acc1 = __builtin_amdgcn_mfma_f32_16x16x32_f16(a, wihf[kk][1], acc1, 0, 0, 0);
    }
    #pragma unroll
    for (int kk = 0; kk < 16; ++kk){
      v8h a = *(const v8h*)(Ah + kk*32);
      acc0 = __builtin_amdgcn_mfma_f32_16x16x32_f16(a, whhf[kk][0], acc0, 0, 0, 0);
      acc1 = __builtin_amdgcn_mfma_f32_16x16x32_f16(a, whhf[kk][1], acc1, 0, 0, 0);
    }

    // ---- gates: lane L holds (i|f) in acc0, (g|o) in acc1; partner is L^8
    h16* drow = dst + (size_t)(t & dstMask) * 64 * 512;
    #pragma unroll
    for (int r = 0; r < 4; ++r){
      float z0 = acc0[r] + bias0;
      float z1 = acc1[r] + bias1;
      float p0 = __shfl_xor(z0, 8, 64);
      float p1 = __shfl_xor(z1, 8, 64);
      float iv = hi ? p0 : z0;
      float fv = hi ? z0 : p0;
      float gv = hi ? p1 : z1;
      float ov = hi ? z1 : p1;
      iv = fsigmoid(iv); fv = fsigmoid(fv); ov = fsigmoid(ov);
      gv = ftanhf(gv);
      c[r] = fv * c[r] + iv * gv;
      float hval = ov * ftanhf(c[r]);
      if (!hi){
        int batch = bg*16 + ((lane >> 4) << 2) + r;
        drow[(size_t)batch * 512 + unit] = (h16)hval;
      }
    }
    __syncthreads();   // drains vmcnt(0): all waves' h stores retired to L2

    if (tid == 0){
      __builtin_amdgcn_fence(__ATOMIC_RELEASE, "agent");   // wbl2: publish h to L3
      __hip_atomic_fetch_add(flagSelf + t, 1u, __ATOMIC_RELAXED, __HIP_MEMORY_SCOPE_AGENT);
    }
  }
}

__global__ __launch_bounds__(256, 1) void lstm_persist(PParams p){
  __shared__ h16 A[16640];   // 33,280 B: in-region 16x520 + h-region 16x520
  const int bx = blockIdx.x;
  const int l  = bx >> 6;
  const int rg = (bx >> 2) & 15;
  const int bg = bx & 3;
  unsigned int* fl = p.flags + (size_t)(l*4 + bg) * 512;
  if (l == 0){
    run_layer<256, true >(p.Wih[0], p.Whh[0], p.bih[0], p.bhh[0], p.x, nullptr,
                          p.s[0], 511, fl, nullptr, rg, bg, A);
  } else {
    unsigned int* fs = p.flags + (size_t)((l-1)*4 + bg) * 512;
    run_layer<512, false>(p.Wih[l], p.Whh[l], p.bih[l], p.bhh[l], nullptr, p.s[l-1],
                          p.s[l], (l == 3) ? 1 : 511, fl, fs, rg, bg, A);
  }
}

__global__ void head_k(const h16* __restrict__ h3, const float* __restrict__ Wo,
                       const float* __restrict__ bo, float* __restrict__ out){
  const int b = blockIdx.x;
  const int lane = threadIdx.x;
  float s = 0.f;
  for (int u = lane; u < 512; u += 64)
    s += (float)h3[(size_t)b * 512 + u] * Wo[u];
  #pragma unroll
  for (int off = 32; off; off >>= 1) s += __shfl_down(s, off, 64);
  if (lane == 0) out[b] = s + bo[0];
}

__global__ void zero_out_k(float* out, int n){
  int i = blockIdx.x * 64 + threadIdx.x;
  if (i < n) out[i] = 0.f;
}

extern "C" void kernel_launch(void* const* d_in, const int* in_sizes, int n_in,
                              void* d_out, int out_size, void* d_ws, size_t ws_size,
                              hipStream_t stream){
  PParams p;
  p.x = (const float*)d_in[0];
  for (int l = 0; l < 4; ++l){
    p.Wih[l] = (const float*)d_in[1 + 4*l + 0];
    p.Whh[l] = (const float*)d_in[1 + 4*l + 1];
    p.bih[l] = (const float*)d_in[1 + 4*l + 2];
    p.bhh[l] = (const float*)d_in[1 + 4*l + 3];
  }
  const float* Wo = (const float*)d_in[17];
  const float* bo = (const float*)d_in[18];

  const size_t FLAG_BYTES = 4 * 4 * 512 * sizeof(unsigned int);   // 32 KB
  const size_t SBYTES     = (size_t)512 * 64 * 512 * 2;           // 32 MB per full stream
  const size_t NEED       = 32768 + 3 * SBYTES + (size_t)2 * 64 * 512 * 2;

  if (ws_size < NEED){
    zero_out_k<<<dim3(1), dim3(64), 0, stream>>>((float*)d_out, out_size);
    return;
  }

  char* ws = (char*)d_ws;
  p.flags = (unsigned int*)ws;
  size_t off = 32768;
  for (int l = 0; l < 3; ++l){ p.s[l] = (h16*)(ws + off); off += SBYTES; }
  p.s[3] = (h16*)(ws + off);

  hipMemsetAsync(p.flags, 0, FLAG_BYTES, stream);

  void* args[] = { &p };
  hipError_t e = hipLaunchCooperativeKernel((void*)lstm_persist, dim3(256), dim3(256),
                                            args, 0, stream);
  if (e != hipSuccess){
    // fallback: plain launch; 256 blocks @ 1 wg/CU co-reside on 256 CUs
    lstm_persist<<<dim3(256), dim3(256), 0, stream>>>(p);
  }

  // final timestep t=511 lives in s3 buffer (511 & 1) == 1
  head_k<<<dim3(64), dim3(64), 0, stream>>>(p.s[3] + (size_t)64 * 512, Wo, bo, (float*)d_out);
}

// Round 2
// 1971.764 us; speedup vs baseline: 2.6226x; 2.6226x over previous
//
#include <hip/hip_runtime.h>
#include <hip/hip_fp16.h>

typedef _Float16 h16;
typedef _Float16 v8h  __attribute__((ext_vector_type(8)));
typedef float    v4f  __attribute__((ext_vector_type(4)));

#define NPROD 16u

struct PParams {
  const float* x;                 // [64][512][256] fp32
  const float* Wih[4];            // [2048][KIN]
  const float* Whh[4];            // [2048][512]
  const float* bih[4];
  const float* bhh[4];
  h16* s[4];                      // streams: l=0..2 [512][64][512], l=3 [2][64][512]
  unsigned int* flags;            // [4][4][512]
};

__device__ inline float fsigmoid(float x){
  float e = __builtin_amdgcn_exp2f(-1.4426950408889634f * __builtin_fabsf(x));
  float r = __builtin_amdgcn_rcpf(1.0f + e);
  return x >= 0.f ? r : e * r;
}
__device__ inline float ftanhf(float x){
  float e = __builtin_amdgcn_exp2f(-2.8853900817779268f * __builtin_fabsf(x));
  float t = (1.0f - e) * __builtin_amdgcn_rcpf(1.0f + e);
  return x >= 0.f ? t : -t;
}

// Fine-grained agent-coherent ops (sc0/sc1): write-through to L3 / read-through
// past the non-coherent per-XCD L2. No whole-cache wbl2/inv fences anywhere.
__device__ inline unsigned int fload(const unsigned int* p){
  return __hip_atomic_load(p, __ATOMIC_RELAXED, __HIP_MEMORY_SCOPE_AGENT);
}
__device__ inline unsigned long long cload64(const void* p){
  return __hip_atomic_load((const unsigned long long*)p, __ATOMIC_RELAXED,
                           __HIP_MEMORY_SCOPE_AGENT);
}
__device__ inline void cstore32(void* p, unsigned int v){
  __hip_atomic_store((unsigned int*)p, v, __ATOMIC_RELAXED, __HIP_MEMORY_SCOPE_AGENT);
}

__device__ inline void wait_flag(const unsigned int* f, unsigned int tgt){
  int it = 0;
  while (fload(f) < tgt){
    __builtin_amdgcn_s_sleep(1);
    if (++it > (1 << 21)) break;   // safety valve: never hang the harness
  }
}

// One LSTM layer slice: this wg owns 32 hidden units x 4 gates for 16 batches.
// Weights live in VGPRs as MFMA B-fragments. c stays in fp32 registers.
// Step = src-phase (stage in(t), W_ih MFMAs) then self-phase (stage h(t-1),
// W_hh MFMAs, gates, publish h). Self-flag pre-checked before the W_ih chain
// so its L3 latency hides behind compute.
template<int KIN, bool XSRC>
__device__ void run_layer(const float* __restrict__ Wih, const float* __restrict__ Whh,
                          const float* __restrict__ bih, const float* __restrict__ bhh,
                          const float* __restrict__ xsrc,
                          const h16* __restrict__ src,
                          h16* __restrict__ dst, int dstMask,
                          unsigned int* flagSelf, unsigned int* flagSrc,
                          int rg, int bg, h16* A)
{
  const int tid  = threadIdx.x;
  const int wv   = tid >> 6;
  const int lane = tid & 63;
  const int ISTR = KIN + 8;       // padded LDS row stride (halves)
  const int HOFF = 8320;          // h-region offset (halves), stride 520
  const int KI   = KIN / 32;

  const int n16  = lane & 15;
  const int unit = rg*32 + wv*8 + (n16 & 7);
  const int ksub = ((lane >> 4) & 3) * 8;
  const int row0 = ((n16 >> 3)    ) * 512 + unit;   // gate i (n<8) / f (n>=8)
  const int row1 = ((n16 >> 3) + 2) * 512 + unit;   // gate g / o

  // ---- prologue: load weight slices into register fragments (one-time)
  v8h wihf[KI][2];
  v8h whhf[16][2];
  #pragma unroll
  for (int kk = 0; kk < KI; ++kk){
    #pragma unroll
    for (int j = 0; j < 2; ++j){
      const float* p = Wih + (size_t)(j ? row1 : row0) * KIN + kk*32 + ksub;
      v8h fr;
      #pragma unroll
      for (int e = 0; e < 8; ++e) fr[e] = (h16)p[e];
      wihf[kk][j] = fr;
    }
  }
  #pragma unroll
  for (int kk = 0; kk < 16; ++kk){
    #pragma unroll
    for (int j = 0; j < 2; ++j){
      const float* p = Whh + (size_t)(j ? row1 : row0) * 512 + kk*32 + ksub;
      v8h fr;
      #pragma unroll
      for (int e = 0; e < 8; ++e) fr[e] = (h16)p[e];
      whhf[kk][j] = fr;
    }
  }
  const float bias0 = bih[row0] + bhh[row0];
  const float bias1 = bih[row1] + bhh[row1];
  float c[4] = {0.f, 0.f, 0.f, 0.f};
  const bool hi = (lane & 8) != 0;

  #pragma unroll 1
  for (int t = 0; t < 512; ++t){
    // ================= phase 1: input from layer below =================
    if (!XSRC && tid == 0) wait_flag(flagSrc + t, NPROD);
    __syncthreads();

    if (XSRC){
      #pragma unroll
      for (int i = 0; i < 2; ++i){
        int q = tid + i*256;
        int row = q >> 5, col = q & 31;          // 32 chunks x 8 halves per row
        const float* xp = xsrc + ((size_t)(bg*16 + row)*512 + t)*256 + col*8;
        float4 v0 = *(const float4*)(xp);
        float4 v1 = *(const float4*)(xp + 4);
        v8h o = {(h16)v0.x,(h16)v0.y,(h16)v0.z,(h16)v0.w,
                 (h16)v1.x,(h16)v1.y,(h16)v1.z,(h16)v1.w};
        *(v8h*)(A + row*ISTR + col*8) = o;
      }
    } else {
      unsigned long long a0[4], a1[4];
      #pragma unroll
      for (int i = 0; i < 4; ++i){
        int q = tid + i*256;
        int row = q >> 6, col = q & 63;          // 64 chunks x 8 halves per row
        const h16* sp = src + ((size_t)t*64 + bg*16 + row)*512 + col*8;
        a0[i] = cload64(sp);
        a1[i] = cload64(sp + 4);
      }
      #pragma unroll
      for (int i = 0; i < 4; ++i){
        int q = tid + i*256;
        int row = q >> 6, col = q & 63;
        union { unsigned long long u[2]; v8h h; } tmp;
        tmp.u[0] = a0[i]; tmp.u[1] = a1[i];
        *(v8h*)(A + row*ISTR + col*8) = tmp.h;
      }
    }
    __syncthreads();

    // pre-check self flag; its L3 latency hides behind the W_ih MFMA chain
    unsigned int pre = NPROD;
    if (tid == 0 && t > 0) pre = fload(flagSelf + t - 1);

    v4f acc0 = {0.f, 0.f, 0.f, 0.f};
    v4f acc1 = {0.f, 0.f, 0.f, 0.f};
    const h16* Ain = A + n16*ISTR + ksub;
    #pragma unroll
    for (int kk = 0; kk < KI; ++kk){
      v8h a = *(const v8h*)(Ain + kk*32);
      acc0 = __builtin_amdgcn_mfma_f32_16x16x32_f16(a, wihf[kk][0], acc0, 0, 0, 0);
      acc1 = __builtin_amdgcn_mfma_f32_16x16x32_f16(a, wihf[kk][1], acc1, 0, 0, 0);
    }

    // ================= phase 2: recurrence =================
    if (tid == 0 && t > 0 && pre < NPROD) wait_flag(flagSelf + t - 1, NPROD);
    __syncthreads();

    if (t == 0){
      #pragma unroll
      for (int i = 0; i < 4; ++i){
        int q = tid + i*256;
        int row = q >> 6, col = q & 63;
        union { unsigned long long u[2]; v8h h; } tmp;
        tmp.u[0] = 0ull; tmp.u[1] = 0ull;
        *(v8h*)(A + HOFF + row*520 + col*8) = tmp.h;
      }
    } else {
      const h16* hsrc = dst + (size_t)((t-1) & dstMask) * 64 * 512;
      unsigned long long a0[4], a1[4];
      #pragma unroll
      for (int i = 0; i < 4; ++i){
        int q = tid + i*256;
        int row = q >> 6, col = q & 63;
        const h16* sp = hsrc + (size_t)(bg*16 + row)*512 + col*8;
        a0[i] = cload64(sp);
        a1[i] = cload64(sp + 4);
      }
      #pragma unroll
      for (int i = 0; i < 4; ++i){
        int q = tid + i*256;
        int row = q >> 6, col = q & 63;
        union { unsigned long long u[2]; v8h h; } tmp;
        tmp.u[0] = a0[i]; tmp.u[1] = a1[i];
        *(v8h*)(A + HOFF + row*520 + col*8) = tmp.h;
      }
    }
    __syncthreads();

    const h16* Ah = A + HOFF + n16*520 + ksub;
    #pragma unroll
    for (int kk = 0; kk < 16; ++kk){
      v8h a = *(const v8h*)(Ah + kk*32);
      acc0 = __builtin_amdgcn_mfma_f32_16x16x32_f16(a, whhf[kk][0], acc0, 0, 0, 0);
      acc1 = __builtin_amdgcn_mfma_f32_16x16x32_f16(a, whhf[kk][1], acc1, 0, 0, 0);
    }

    // ---- gates: lane L holds (i|f) in acc0, (g|o) in acc1; partner is L^8
    h16* drow = dst + (size_t)(t & dstMask) * 64 * 512;
    #pragma unroll
    for (int r = 0; r < 4; ++r){
      float z0 = acc0[r] + bias0;
      float z1 = acc1[r] + bias1;
      float p0 = __shfl_xor(z0, 8, 64);
      float p1 = __shfl_xor(z1, 8, 64);
      float iv = hi ? p0 : z0;
      float fv = hi ? z0 : p0;
      float gv = hi ? p1 : z1;
      float ov = hi ? z1 : p1;
      iv = fsigmoid(iv); fv = fsigmoid(fv); ov = fsigmoid(ov);
      gv = ftanhf(gv);
      c[r] = fv * c[r] + iv * gv;
      float hval = ov * ftanhf(c[r]);
      h16 hh = (h16)hval;
      unsigned int mine = (unsigned int)__builtin_bit_cast(unsigned short, hh);
      unsigned int partner = (unsigned int)__shfl_xor((int)mine, 1, 64);
      if (!hi && !(n16 & 1)){
        int batch = bg*16 + ((lane >> 4) << 2) + r;
        // packed 2-unit write-through store (sc0 sc1) -> visible in L3
        cstore32((void*)(drow + (size_t)batch*512 + unit), mine | (partner << 16));
      }
    }
    __syncthreads();   // each wave's vmcnt(0) drains write-through stores to L3

    if (tid == 0)
      __hip_atomic_fetch_add(flagSelf + t, 1u, __ATOMIC_RELAXED, __HIP_MEMORY_SCOPE_AGENT);
  }
}

__global__ __launch_bounds__(256, 1) void lstm_persist(PParams p){
  __shared__ h16 A[16640];   // 33,280 B: in-region 16x520 + h-region 16x520
  const int bx = blockIdx.x;
  const int l  = bx >> 6;
  const int rg = (bx >> 2) & 15;
  const int bg = bx & 3;
  unsigned int* fl = p.flags + (size_t)(l*4 + bg) * 512;
  if (l == 0){
    run_layer<256, true >(p.Wih[0], p.Whh[0], p.bih[0], p.bhh[0], p.x, nullptr,
                          p.s[0], 511, fl, nullptr, rg, bg, A);
  } else {
    unsigned int* fs = p.flags + (size_t)((l-1)*4 + bg) * 512;
    run_layer<512, false>(p.Wih[l], p.Whh[l], p.bih[l], p.bhh[l], nullptr, p.s[l-1],
                          p.s[l], (l == 3) ? 1 : 511, fl, fs, rg, bg, A);
  }
}

__global__ void head_k(const h16* __restrict__ h3, const float* __restrict__ Wo,
                       const float* __restrict__ bo, float* __restrict__ out){
  const int b = blockIdx.x;
  const int lane = threadIdx.x;
  float s = 0.f;
  for (int u = lane; u < 512; u += 64)
    s += (float)h3[(size_t)b * 512 + u] * Wo[u];
  #pragma unroll
  for (int off = 32; off; off >>= 1) s += __shfl_down(s, off, 64);
  if (lane == 0) out[b] = s + bo[0];
}

__global__ void zero_out_k(float* out, int n){
  int i = blockIdx.x * 64 + threadIdx.x;
  if (i < n) out[i] = 0.f;
}

extern "C" void kernel_launch(void* const* d_in, const int* in_sizes, int n_in,
                              void* d_out, int out_size, void* d_ws, size_t ws_size,
                              hipStream_t stream){
  PParams p;
  p.x = (const float*)d_in[0];
  for (int l = 0; l < 4; ++l){
    p.Wih[l] = (const float*)d_in[1 + 4*l + 0];
    p.Whh[l] = (const float*)d_in[1 + 4*l + 1];
    p.bih[l] = (const float*)d_in[1 + 4*l + 2];
    p.bhh[l] = (const float*)d_in[1 + 4*l + 3];
  }
  const float* Wo = (const float*)d_in[17];
  const float* bo = (const float*)d_in[18];

  const size_t FLAG_BYTES = 4 * 4 * 512 * sizeof(unsigned int);   // 32 KB
  const size_t SBYTES     = (size_t)512 * 64 * 512 * 2;           // 32 MB per full stream
  const size_t NEED       = 32768 + 3 * SBYTES + (size_t)2 * 64 * 512 * 2;

  if (ws_size < NEED){
    zero_out_k<<<dim3(1), dim3(64), 0, stream>>>((float*)d_out, out_size);
    return;
  }

  char* ws = (char*)d_ws;
  p.flags = (unsigned int*)ws;
  size_t off = 32768;
  for (int l = 0; l < 3; ++l){ p.s[l] = (h16*)(ws + off); off += SBYTES; }
  p.s[3] = (h16*)(ws + off);

  hipMemsetAsync(p.flags, 0, FLAG_BYTES, stream);

  void* args[] = { &p };
  hipError_t e = hipLaunchCooperativeKernel((void*)lstm_persist, dim3(256), dim3(256),
                                            args, 0, stream);
  if (e != hipSuccess){
    // fallback: plain launch; 256 blocks @ 1 wg/CU co-reside on 256 CUs
    lstm_persist<<<dim3(256), dim3(256), 0, stream>>>(p);
  }

  // final timestep t=511 lives in s3 buffer (511 & 1) == 1
  head_k<<<dim3(64), dim3(64), 0, stream>>>(p.s[3] + (size_t)64 * 512, Wo, bo, (float*)d_out);
}